// Round 10
// baseline (291.227 us; speedup 1.0000x reference)
//
#include <hip/hip_runtime.h>
#include <hip/hip_bf16.h>

// ---------------------------------------------------------------------------
// GCN graph classifier: 2x GCNConv(relu) -> mean pool -> MLP -> sigmoid
// Round 10: 8-deep gather unroll in agg; decoupled-lookback single-kernel
// scan (device-scope atomics, 300 co-resident blocks); mean-pool fused into
// layer-2 agg (no abuf store) with XCD-split padded atomic accumulators.
// Build = stable multisplit (no global atomics) -> sorted CSR.
// h' = dinv*(A@W) via MFMA; out = relu(dinv*(sum h'[nbr] + h'[self]) + b).
// 9 kernel launches total.
// ---------------------------------------------------------------------------

#define TILE 128
#define EPB 4096  // edges per multisplit block

using short8 = __attribute__((ext_vector_type(8))) short;   // 8 bf16 (4 VGPR)
using f32x4  = __attribute__((ext_vector_type(4))) float;   // MFMA accum

__device__ inline unsigned short f2bf(float f) {  // RNE fp32 -> bf16
    unsigned u = __float_as_uint(f);
    u = (u + 0x7fff + ((u >> 16) & 1)) >> 16;
    return (unsigned short)u;
}
__device__ inline float bf2f(unsigned short b) {
    return __uint_as_float((unsigned)b << 16);
}
__device__ inline void acc8(float* a, const uint4 v) {
    a[0] += bf2f((unsigned short)(v.x & 0xffff));
    a[1] += bf2f((unsigned short)(v.x >> 16));
    a[2] += bf2f((unsigned short)(v.y & 0xffff));
    a[3] += bf2f((unsigned short)(v.y >> 16));
    a[4] += bf2f((unsigned short)(v.z & 0xffff));
    a[5] += bf2f((unsigned short)(v.z >> 16));
    a[6] += bf2f((unsigned short)(v.w & 0xffff));
    a[7] += bf2f((unsigned short)(v.w >> 16));
}

// ---- histA: per-block LDS histogram of dst tiles; + prepw + zero pool/state
// wf[((ct*4+ks)*64+l)*8+j] = W[ks*32 + (l>>4)*8 + j][ct*16 + (l&15)]
__global__ __launch_bounds__(256) void k_histA(
    const int* __restrict__ dst, int* __restrict__ hist,
    float* __restrict__ poolp, int* __restrict__ state,
    const float* __restrict__ w1, const float* __restrict__ w2,
    unsigned short* __restrict__ wf1, unsigned short* __restrict__ wf2,
    int e, int nt, int nb) {
    __shared__ int h[512];
    const int tid = threadIdx.x, b = blockIdx.x;
    for (int i = tid; i < 512; i += 256) h[i] = 0;
    if (b < 8)  // zero the 8 XCD-split padded pool accumulators (2048 each)
        for (int i = tid; i < 2048; i += 256) poolp[b * 2048 + i] = 0.0f;
    if (b == 8)  // zero scan lookback state
        for (int i = tid; i < 512; i += 256) state[i] = 0;
    // fused weight prep: blocks 0..127 each convert 256 elements
    if (b < 128) {
        const int t = b * 256 + tid;  // 0..32767
        const int i = t & 16383;
        const int j = i & 7;
        const int l = (i >> 3) & 63;
        const int ks = (i >> 9) & 3;
        const int ct = (i >> 11) & 7;
        const int k = ks * 32 + (l >> 4) * 8 + j;
        const int c = ct * 16 + (l & 15);
        if (t < 16384)
            wf1[i] = f2bf(w1[k * 128 + c]);
        else
            wf2[i] = f2bf(w2[k * 128 + c]);
    }
    __syncthreads();
    const int base = b * EPB;
#pragma unroll
    for (int k = 0; k < EPB / 256; ++k) {
        const int i = base + k * 256 + tid;
        if (i < e) atomicAdd(&h[dst[i] >> 7], 1);
    }
    __syncthreads();
    for (int t = tid; t < nt; t += 256) hist[t * nb + b] = h[t];
}

// ---- single-kernel exclusive scan: decoupled lookback (wave-parallel) ------
// state[b]: bit31 = inclusive-prefix known, bit30 = aggregate known, low 30 = value
__global__ __launch_bounds__(256) void k_scanLB(const int* __restrict__ in,
                                                int* __restrict__ outp,
                                                int* __restrict__ state,
                                                int n) {
    __shared__ int sh[256];
    __shared__ int sprefix;
    const int b = blockIdx.x, tid = threadIdx.x;
    const int i = b * 256 + tid;
    int v = (i < n) ? in[i] : 0;
    sh[tid] = v;
    __syncthreads();
    for (int o = 1; o < 256; o <<= 1) {
        int t = (tid >= o) ? sh[tid - o] : 0;
        __syncthreads();
        sh[tid] += t;
        __syncthreads();
    }
    const int total = sh[255];
    if (tid == 0) {
        const int val =
            (b == 0) ? (total | (int)0x80000000) : (total | 0x40000000);
        __hip_atomic_store(&state[b], val, __ATOMIC_RELEASE,
                           __HIP_MEMORY_SCOPE_AGENT);
        if (b == 0) sprefix = 0;
    }
    if (b > 0 && tid < 64) {
        int pre = 0;
        int j = b - 1;
        while (true) {
            const int jj = j - tid;
            int s = (jj >= 0)
                        ? __hip_atomic_load(&state[jj], __ATOMIC_ACQUIRE,
                                            __HIP_MEMORY_SCOPE_AGENT)
                        : (int)0x80000000;  // virtual inclusive 0 before block 0
            const unsigned long long incl =
                __ballot(((unsigned)s & 0x80000000u) != 0);
            const unsigned long long inval = __ballot((s & 0xC0000000) == 0);
            if (incl != 0) {
                const int li = (int)(__ffsll((unsigned long long)incl) - 1);
                const unsigned long long below =
                    (li == 0) ? 0ULL : ((1ULL << li) - 1ULL);
                if (inval & below) continue;  // unknown entry nearer than inclusive
                int c = (tid <= li) ? (s & 0x3fffffff) : 0;
#pragma unroll
                for (int o2 = 1; o2 < 64; o2 <<= 1) c += __shfl_xor(c, o2);
                pre += c;
                break;
            } else {
                if (inval != 0) continue;  // some aggregates not yet published
                int c = s & 0x3fffffff;    // all 64 are valid aggregates
#pragma unroll
                for (int o2 = 1; o2 < 64; o2 <<= 1) c += __shfl_xor(c, o2);
                pre += c;
                j -= 64;
            }
        }
        if (tid == 0) {
            __hip_atomic_store(&state[b],
                               ((total + pre) & 0x3fffffff) | (int)0x80000000,
                               __ATOMIC_RELEASE, __HIP_MEMORY_SCOPE_AGENT);
            sprefix = pre;
        }
    }
    __syncthreads();
    if (i < n) outp[i] = sh[tid] - v + sprefix;
}

// ---- passB: stable multisplit scatter into exact (tile,block) chunks -------
__global__ __launch_bounds__(256) void k_passB(const int* __restrict__ ei,
                                               const int* __restrict__ histS,
                                               unsigned* __restrict__ bin,
                                               int e, int nt, int nb) {
    __shared__ int cnt[512], basei[512];
    const int tid = threadIdx.x, b = blockIdx.x;
    for (int i = tid; i < 512; i += 256) cnt[i] = 0;
    for (int t = tid; t < nt; t += 256) basei[t] = histS[t * nb + b];
    __syncthreads();
    const int base = b * EPB;
#pragma unroll
    for (int k = 0; k < EPB / 256; ++k) {
        const int i = base + k * 256 + tid;
        if (i < e) {
            const int s = ei[i];
            const int d = ei[e + i];
            const int t = d >> 7;
            const int r = atomicAdd(&cnt[t], 1);
            bin[basei[t] + r] = ((unsigned)s << 7) | (unsigned)(d & 127);
        }
    }
}

// ---- per-tile LDS counting sort: bin segment -> sorted csr + rowptr + dinv -
__global__ __launch_bounds__(256) void k_sortT(const unsigned* __restrict__ bin,
                                               const int* __restrict__ histS,
                                               unsigned* __restrict__ csr,
                                               int* __restrict__ rowptr,
                                               float* __restrict__ dinv,
                                               int n, int nt, int nb, int etot) {
    __shared__ int deg[TILE], lrow[TILE], cur[TILE];
    const int t = blockIdx.x, tid = threadIdx.x;
    if (tid < TILE) {
        deg[tid] = 0;
        cur[tid] = 0;
    }
    __syncthreads();
    const int b = histS[t * nb];
    const int e = (t + 1 < nt) ? histS[(t + 1) * nb] : etot;
    for (int j = b + tid; j < e; j += 256) atomicAdd(&deg[bin[j] & 127], 1);
    __syncthreads();
    if (tid < TILE) lrow[tid] = deg[tid];
    __syncthreads();
    for (int o = 1; o < TILE; o <<= 1) {
        int v = (tid >= o && tid < TILE) ? lrow[tid - o] : 0;
        __syncthreads();
        if (tid < TILE) lrow[tid] += v;
        __syncthreads();
    }
    if (tid < TILE) {
        const int excl = lrow[tid] - deg[tid];
        rowptr[t * TILE + tid] = b + excl;
        const int node = t * TILE + tid;
        if (node < n) dinv[node] = rsqrtf((float)deg[tid] + 1.0f);
        lrow[tid] = excl;
    }
    if (tid == 0) rowptr[t * TILE + TILE] = e;
    __syncthreads();
    for (int j = b + tid; j < e; j += 256) {
        const unsigned r = bin[j];
        const int dl = r & 127;
        const int p = atomicAdd(&cur[dl], 1);
        csr[b + lrow[dl] + p] = r >> 7;
    }
}

// ---- MFMA bf16 GEMM + dinv-scale epilogue: C = dinv[r]*(A@W), bf16 out -----
// 4 waves/block, 16 rows/wave. 16x16x32 frags; D: col=lane&15, row=(lane>>4)*4+i
template <bool AFP32>
__global__ __launch_bounds__(256) void k_gemm_mfma(
    const void* __restrict__ Ain, const unsigned short* __restrict__ Wf,
    const float* __restrict__ dinv, unsigned short* __restrict__ Cout,
    int nrows) {
    const int tid = threadIdx.x;
    const int wave = tid >> 6, l = tid & 63;
    const int r0w = blockIdx.x * 64 + wave * 16;
    const int mrow = l & 15, koff = (l >> 4) * 8;
    int r = r0w + mrow;
    int rload = (r < nrows) ? r : 0;

    short8 afr[4];
    if (AFP32) {
        const float* A = (const float*)Ain;
#pragma unroll
        for (int ks = 0; ks < 4; ++ks) {
            const float4 lo = *(const float4*)&A[(size_t)rload * 128 + ks * 32 + koff];
            const float4 hi = *(const float4*)&A[(size_t)rload * 128 + ks * 32 + koff + 4];
            short8 t;
            t[0] = (short)f2bf(lo.x); t[1] = (short)f2bf(lo.y);
            t[2] = (short)f2bf(lo.z); t[3] = (short)f2bf(lo.w);
            t[4] = (short)f2bf(hi.x); t[5] = (short)f2bf(hi.y);
            t[6] = (short)f2bf(hi.z); t[7] = (short)f2bf(hi.w);
            afr[ks] = t;
        }
    } else {
        const unsigned short* A = (const unsigned short*)Ain;
#pragma unroll
        for (int ks = 0; ks < 4; ++ks)
            afr[ks] = *(const short8*)&A[(size_t)rload * 128 + ks * 32 + koff];
    }

    f32x4 acc[8];
#pragma unroll
    for (int ct = 0; ct < 8; ++ct) acc[ct] = (f32x4){0.f, 0.f, 0.f, 0.f};

#pragma unroll
    for (int ct = 0; ct < 8; ++ct) {
#pragma unroll
        for (int ks = 0; ks < 4; ++ks) {
            const short8 b = *(const short8*)&Wf[((ct * 4 + ks) * 64 + l) * 8];
            acc[ct] = __builtin_amdgcn_mfma_f32_16x16x32_bf16(afr[ks], b,
                                                              acc[ct], 0, 0, 0);
        }
    }

    const int rs0 = r0w + (l >> 4) * 4;
    const int cc = l & 15;
    float dv[4];
#pragma unroll
    for (int i = 0; i < 4; ++i)
        dv[i] = (rs0 + i < nrows) ? dinv[rs0 + i] : 0.f;
#pragma unroll
    for (int ct = 0; ct < 8; ++ct) {
#pragma unroll
        for (int i = 0; i < 4; ++i) {
            const int rr = rs0 + i;
            if (rr < nrows)
                Cout[(size_t)rr * 128 + ct * 16 + cc] = f2bf(acc[ct][i] * dv[i]);
        }
    }
}

// ---- aggregate: 4 nodes/wave, 16 lanes x uint4/row, 8-deep gather unroll ---
// out[d] = relu(dinv[d]*(sum h'[s] + h'[d]) + b); POOL: fused mean-pool,
// no out store (layer-2 output feeds only the pool).
template <bool POOL>
__global__ __launch_bounds__(256) void k_agg(
    const uint4* __restrict__ hp4,  // h' as uint4[n][16]
    const float* __restrict__ dinv, const int* __restrict__ rowptr,
    const unsigned* __restrict__ csr, const float* __restrict__ bias,
    uint4* __restrict__ outp4, float* __restrict__ poolp, int n) {
    __shared__ float psh[4][128];
    const int wave = threadIdx.x >> 6, lane = threadIdx.x & 63;
    const int g = lane >> 4, sl = lane & 15;
    const int node = (blockIdx.x * 4 + wave) * 4 + g;
    const bool valid = node < n;
    const int nd = valid ? node : 0;

    const int rb = rowptr[nd];
    const int deg = valid ? (rowptr[nd + 1] - rb) : 0;
    int maxd = deg;
    maxd = max(maxd, __shfl_xor(maxd, 16));
    maxd = max(maxd, __shfl_xor(maxd, 32));

    const uint4 z = {0u, 0u, 0u, 0u};
    float acc[8];
#pragma unroll
    for (int k = 0; k < 8; ++k) acc[k] = 0.f;
    {
        uint4 self = valid ? hp4[(size_t)nd * 16 + sl] : z;
        acc8(acc, self);
    }

    int j = 0;
    for (; j + 7 < maxd; j += 8) {  // 8 gathers in flight
        int id[8];
#pragma unroll
        for (int k = 0; k < 8; ++k)
            id[k] = (j + k < deg) ? (int)csr[rb + j + k] : -1;
        uint4 v[8];
#pragma unroll
        for (int k = 0; k < 8; ++k)
            v[k] = (id[k] >= 0) ? hp4[(size_t)id[k] * 16 + sl] : z;
#pragma unroll
        for (int k = 0; k < 8; ++k) acc8(acc, v[k]);
    }
    for (; j + 3 < maxd; j += 4) {
        int id[4];
#pragma unroll
        for (int k = 0; k < 4; ++k)
            id[k] = (j + k < deg) ? (int)csr[rb + j + k] : -1;
        uint4 v[4];
#pragma unroll
        for (int k = 0; k < 4; ++k)
            v[k] = (id[k] >= 0) ? hp4[(size_t)id[k] * 16 + sl] : z;
#pragma unroll
        for (int k = 0; k < 4; ++k) acc8(acc, v[k]);
    }
    for (; j < maxd; ++j) {
        uint4 v0 = (j < deg) ? hp4[(size_t)csr[rb + j] * 16 + sl] : z;
        acc8(acc, v0);
    }

    const float dv = valid ? dinv[nd] : 0.f;
    const float4 b0 = ((const float4*)bias)[sl * 2];
    const float4 b1 = ((const float4*)bias)[sl * 2 + 1];
    float o[8];
    o[0] = fmaxf(acc[0] * dv + b0.x, 0.f);
    o[1] = fmaxf(acc[1] * dv + b0.y, 0.f);
    o[2] = fmaxf(acc[2] * dv + b0.z, 0.f);
    o[3] = fmaxf(acc[3] * dv + b0.w, 0.f);
    o[4] = fmaxf(acc[4] * dv + b1.x, 0.f);
    o[5] = fmaxf(acc[5] * dv + b1.y, 0.f);
    o[6] = fmaxf(acc[6] * dv + b1.z, 0.f);
    o[7] = fmaxf(acc[7] * dv + b1.w, 0.f);
    if (!valid) {
#pragma unroll
        for (int k = 0; k < 8; ++k) o[k] = 0.f;
    }

    if (!POOL) {
        if (valid) {
            uint4 ov;
            ov.x = ((unsigned)f2bf(o[1]) << 16) | f2bf(o[0]);
            ov.y = ((unsigned)f2bf(o[3]) << 16) | f2bf(o[2]);
            ov.z = ((unsigned)f2bf(o[5]) << 16) | f2bf(o[4]);
            ov.w = ((unsigned)f2bf(o[7]) << 16) | f2bf(o[6]);
            outp4[(size_t)nd * 16 + sl] = ov;
        }
    } else {
        // column sums: reduce over 4 groups in-wave, 4 waves via LDS,
        // then one padded atomicAdd per column into the XCD-split slot.
        float s[8];
#pragma unroll
        for (int k = 0; k < 8; ++k) {
            float t = o[k];
            t += __shfl_xor(t, 16);
            t += __shfl_xor(t, 32);
            s[k] = t;
        }
        if (lane < 16) {
#pragma unroll
            for (int k = 0; k < 8; ++k) psh[wave][sl * 8 + k] = s[k];
        }
        __syncthreads();
        const int tid = threadIdx.x;
        if (tid < 128) {
            const float t =
                psh[0][tid] + psh[1][tid] + psh[2][tid] + psh[3][tid];
            atomicAdd(&poolp[((blockIdx.x & 7) << 11) + tid * 16], t);
        }
    }
}

// ---- MLP head: single block, 128 threads -----------------------------------
__global__ __launch_bounds__(128) void k_mlp(
    const float* __restrict__ poolp, const float* __restrict__ w11,
    const float* __restrict__ b11, const float* __restrict__ w12,
    const float* __restrict__ b12, const float* __restrict__ w21,
    const float* __restrict__ b21, const float* __restrict__ w22,
    const float* __restrict__ b22, float* __restrict__ out, int n) {
    __shared__ float g[128], t1[128], t2[128], t3[128], red[128];
    const int tid = threadIdx.x;
    float gs = 0.f;
#pragma unroll
    for (int x = 0; x < 8; ++x) gs += poolp[x * 2048 + tid * 16];
    g[tid] = gs * (1.0f / (float)n);
    __syncthreads();

    float s = b11[tid];
    for (int k = 0; k < 128; ++k) s += g[k] * w11[k * 128 + tid];
    t1[tid] = fmaxf(s, 0.f);
    __syncthreads();

    s = b12[tid];
    for (int k = 0; k < 128; ++k) s += t1[k] * w12[k * 128 + tid];
    t2[tid] = s;
    __syncthreads();

    s = b21[tid];
    for (int k = 0; k < 128; ++k) s += t2[k] * w21[k * 128 + tid];
    t3[tid] = fmaxf(s, 0.f);
    __syncthreads();

    red[tid] = t3[tid] * w22[tid];
    __syncthreads();
    if (tid == 0) {
        float z = b22[0];
        for (int k = 0; k < 128; ++k) z += red[k];
        out[0] = 1.0f / (1.0f + expf(-z));
    }
}

extern "C" void kernel_launch(void* const* d_in, const int* in_sizes, int n_in,
                              void* d_out, int out_size, void* d_ws,
                              size_t ws_size, hipStream_t stream) {
    const float* x = (const float*)d_in[0];
    const int* ei = (const int*)d_in[1];
    const float* c1w = (const float*)d_in[2];
    const float* c1b = (const float*)d_in[3];
    const float* c2w = (const float*)d_in[4];
    const float* c2b = (const float*)d_in[5];
    const float* f1w1 = (const float*)d_in[6];
    const float* f1b1 = (const float*)d_in[7];
    const float* f1w2 = (const float*)d_in[8];
    const float* f1b2 = (const float*)d_in[9];
    const float* f2w1 = (const float*)d_in[10];
    const float* f2b1 = (const float*)d_in[11];
    const float* f2w2 = (const float*)d_in[12];
    const float* f2b2 = (const float*)d_in[13];
    float* out = (float*)d_out;

    const int N = in_sizes[0] / 128;
    const int E = in_sizes[1] / 2;
    const int NT = (N + TILE - 1) / TILE;    // 391
    const int NB = (E + EPB - 1) / EPB;      // 196
    const int NTB = NT * NB;                 // 76,636
    const int nbScan = (NTB + 255) / 256;    // 300 (<=512: state fits)

    char* ws = (char*)d_ws;
    size_t off = 0;
    auto alloc = [&](size_t b) {
        size_t o = off;
        off += (b + 255) & ~(size_t)255;
        return o;
    };
    int* hist = (int*)(ws + alloc((size_t)NTB * 4));
    int* histS = (int*)(ws + alloc((size_t)NTB * 4));
    int* state = (int*)(ws + alloc(2048));
    unsigned* bin = (unsigned*)(ws + alloc((size_t)E * 4));
    unsigned* csr = (unsigned*)(ws + alloc((size_t)E * 4));
    int* rowptr = (int*)(ws + alloc((size_t)(NT * TILE + 1) * 4));
    float* dinv = (float*)(ws + alloc((size_t)N * 4));
    float* poolp = (float*)(ws + alloc(8 * 2048 * 4));  // 8 XCD slots, 64B-padded
    unsigned short* wf1 = (unsigned short*)(ws + alloc(16384 * 2));
    unsigned short* wf2 = (unsigned short*)(ws + alloc(16384 * 2));
    unsigned short* hbuf = (unsigned short*)(ws + alloc((size_t)N * 128 * 2));
    unsigned short* abuf = (unsigned short*)(ws + alloc((size_t)N * 128 * 2));

    const int nbG = (N + 63) / 64;  // 782

    k_histA<<<NB, 256, 0, stream>>>(ei + E, hist, poolp, state, c1w, c2w, wf1,
                                    wf2, E, NT, NB);
    k_scanLB<<<nbScan, 256, 0, stream>>>(hist, histS, state, NTB);
    k_passB<<<NB, 256, 0, stream>>>(ei, histS, bin, E, NT, NB);
    k_sortT<<<NT, 256, 0, stream>>>(bin, histS, csr, rowptr, dinv, N, NT, NB, E);

    k_gemm_mfma<true><<<nbG, 256, 0, stream>>>(x, wf1, dinv, hbuf, N);
    k_agg<false><<<(N + 15) / 16, 256, 0, stream>>>(
        (const uint4*)hbuf, dinv, rowptr, csr, c1b, (uint4*)abuf, poolp, N);
    k_gemm_mfma<false><<<nbG, 256, 0, stream>>>(abuf, wf2, dinv, hbuf, N);
    k_agg<true><<<(N + 15) / 16, 256, 0, stream>>>(
        (const uint4*)hbuf, dinv, rowptr, csr, c2b, (uint4*)abuf, poolp, N);

    k_mlp<<<1, 128, 0, stream>>>(poolp, f1w1, f1b1, f1w2, f1b2, f2w1, f2b1,
                                 f2w2, f2b2, out, N);
}

// Round 12
// 289.761 us; speedup vs baseline: 1.0051x; 1.0051x over previous
//
#include <hip/hip_runtime.h>
#include <hip/hip_bf16.h>

// ---------------------------------------------------------------------------
// GCN graph classifier: 2x GCNConv(relu) -> mean pool -> MLP -> sigmoid
// Round 11: agg = 4-deep predicated gathers (known-good) + software-pipelined
// csr index prefetch (index load overlaps row-gather latency).
// Keep: decoupled-lookback scan, mean-pool fused into layer-2 agg,
// stable-multisplit build -> sorted CSR, MFMA GEMMs with dinv epilogue.
// 9 kernel launches total.
// ---------------------------------------------------------------------------

#define TILE 128
#define EPB 4096  // edges per multisplit block

using short8 = __attribute__((ext_vector_type(8))) short;   // 8 bf16 (4 VGPR)
using f32x4  = __attribute__((ext_vector_type(4))) float;   // MFMA accum

__device__ inline unsigned short f2bf(float f) {  // RNE fp32 -> bf16
    unsigned u = __float_as_uint(f);
    u = (u + 0x7fff + ((u >> 16) & 1)) >> 16;
    return (unsigned short)u;
}
__device__ inline float bf2f(unsigned short b) {
    return __uint_as_float((unsigned)b << 16);
}
__device__ inline void acc8(float* a, const uint4 v) {
    a[0] += bf2f((unsigned short)(v.x & 0xffff));
    a[1] += bf2f((unsigned short)(v.x >> 16));
    a[2] += bf2f((unsigned short)(v.y & 0xffff));
    a[3] += bf2f((unsigned short)(v.y >> 16));
    a[4] += bf2f((unsigned short)(v.z & 0xffff));
    a[5] += bf2f((unsigned short)(v.z >> 16));
    a[6] += bf2f((unsigned short)(v.w & 0xffff));
    a[7] += bf2f((unsigned short)(v.w >> 16));
}

// ---- histA: per-block LDS histogram of dst tiles; + prepw + zero pool/state
// wf[((ct*4+ks)*64+l)*8+j] = W[ks*32 + (l>>4)*8 + j][ct*16 + (l&15)]
__global__ __launch_bounds__(256) void k_histA(
    const int* __restrict__ dst, int* __restrict__ hist,
    float* __restrict__ poolp, int* __restrict__ state,
    const float* __restrict__ w1, const float* __restrict__ w2,
    unsigned short* __restrict__ wf1, unsigned short* __restrict__ wf2,
    int e, int nt, int nb) {
    __shared__ int h[512];
    const int tid = threadIdx.x, b = blockIdx.x;
    for (int i = tid; i < 512; i += 256) h[i] = 0;
    if (b < 8)  // zero the 8 XCD-split padded pool accumulators (2048 each)
        for (int i = tid; i < 2048; i += 256) poolp[b * 2048 + i] = 0.0f;
    if (b == 8)  // zero scan lookback state
        for (int i = tid; i < 512; i += 256) state[i] = 0;
    // fused weight prep: blocks 0..127 each convert 256 elements
    if (b < 128) {
        const int t = b * 256 + tid;  // 0..32767
        const int i = t & 16383;
        const int j = i & 7;
        const int l = (i >> 3) & 63;
        const int ks = (i >> 9) & 3;
        const int ct = (i >> 11) & 7;
        const int k = ks * 32 + (l >> 4) * 8 + j;
        const int c = ct * 16 + (l & 15);
        if (t < 16384)
            wf1[i] = f2bf(w1[k * 128 + c]);
        else
            wf2[i] = f2bf(w2[k * 128 + c]);
    }
    __syncthreads();
    const int base = b * EPB;
#pragma unroll
    for (int k = 0; k < EPB / 256; ++k) {
        const int i = base + k * 256 + tid;
        if (i < e) atomicAdd(&h[dst[i] >> 7], 1);
    }
    __syncthreads();
    for (int t = tid; t < nt; t += 256) hist[t * nb + b] = h[t];
}

// ---- single-kernel exclusive scan: decoupled lookback (wave-parallel) ------
// state[b]: bit31 = inclusive-prefix known, bit30 = aggregate known, low 30 = value
__global__ __launch_bounds__(256) void k_scanLB(const int* __restrict__ in,
                                                int* __restrict__ outp,
                                                int* __restrict__ state,
                                                int n) {
    __shared__ int sh[256];
    __shared__ int sprefix;
    const int b = blockIdx.x, tid = threadIdx.x;
    const int i = b * 256 + tid;
    int v = (i < n) ? in[i] : 0;
    sh[tid] = v;
    __syncthreads();
    for (int o = 1; o < 256; o <<= 1) {
        int t = (tid >= o) ? sh[tid - o] : 0;
        __syncthreads();
        sh[tid] += t;
        __syncthreads();
    }
    const int total = sh[255];
    if (tid == 0) {
        const int val =
            (b == 0) ? (total | (int)0x80000000) : (total | 0x40000000);
        __hip_atomic_store(&state[b], val, __ATOMIC_RELEASE,
                           __HIP_MEMORY_SCOPE_AGENT);
        if (b == 0) sprefix = 0;
    }
    if (b > 0 && tid < 64) {
        int pre = 0;
        int j = b - 1;
        while (true) {
            const int jj = j - tid;
            int s = (jj >= 0)
                        ? __hip_atomic_load(&state[jj], __ATOMIC_ACQUIRE,
                                            __HIP_MEMORY_SCOPE_AGENT)
                        : (int)0x80000000;  // virtual inclusive 0 before block 0
            const unsigned long long incl =
                __ballot(((unsigned)s & 0x80000000u) != 0);
            const unsigned long long inval = __ballot((s & 0xC0000000) == 0);
            if (incl != 0) {
                const int li = (int)(__ffsll((unsigned long long)incl) - 1);
                const unsigned long long below =
                    (li == 0) ? 0ULL : ((1ULL << li) - 1ULL);
                if (inval & below) continue;  // unknown entry nearer than inclusive
                int c = (tid <= li) ? (s & 0x3fffffff) : 0;
#pragma unroll
                for (int o2 = 1; o2 < 64; o2 <<= 1) c += __shfl_xor(c, o2);
                pre += c;
                break;
            } else {
                if (inval != 0) continue;  // some aggregates not yet published
                int c = s & 0x3fffffff;    // all 64 are valid aggregates
#pragma unroll
                for (int o2 = 1; o2 < 64; o2 <<= 1) c += __shfl_xor(c, o2);
                pre += c;
                j -= 64;
            }
        }
        if (tid == 0) {
            __hip_atomic_store(&state[b],
                               ((total + pre) & 0x3fffffff) | (int)0x80000000,
                               __ATOMIC_RELEASE, __HIP_MEMORY_SCOPE_AGENT);
            sprefix = pre;
        }
    }
    __syncthreads();
    if (i < n) outp[i] = sh[tid] - v + sprefix;
}

// ---- passB: stable multisplit scatter into exact (tile,block) chunks -------
__global__ __launch_bounds__(256) void k_passB(const int* __restrict__ ei,
                                               const int* __restrict__ histS,
                                               unsigned* __restrict__ bin,
                                               int e, int nt, int nb) {
    __shared__ int cnt[512], basei[512];
    const int tid = threadIdx.x, b = blockIdx.x;
    for (int i = tid; i < 512; i += 256) cnt[i] = 0;
    for (int t = tid; t < nt; t += 256) basei[t] = histS[t * nb + b];
    __syncthreads();
    const int base = b * EPB;
#pragma unroll
    for (int k = 0; k < EPB / 256; ++k) {
        const int i = base + k * 256 + tid;
        if (i < e) {
            const int s = ei[i];
            const int d = ei[e + i];
            const int t = d >> 7;
            const int r = atomicAdd(&cnt[t], 1);
            bin[basei[t] + r] = ((unsigned)s << 7) | (unsigned)(d & 127);
        }
    }
}

// ---- per-tile LDS counting sort: bin segment -> sorted csr + rowptr + dinv -
__global__ __launch_bounds__(256) void k_sortT(const unsigned* __restrict__ bin,
                                               const int* __restrict__ histS,
                                               unsigned* __restrict__ csr,
                                               int* __restrict__ rowptr,
                                               float* __restrict__ dinv,
                                               int n, int nt, int nb, int etot) {
    __shared__ int deg[TILE], lrow[TILE], cur[TILE];
    const int t = blockIdx.x, tid = threadIdx.x;
    if (tid < TILE) {
        deg[tid] = 0;
        cur[tid] = 0;
    }
    __syncthreads();
    const int b = histS[t * nb];
    const int e = (t + 1 < nt) ? histS[(t + 1) * nb] : etot;
    for (int j = b + tid; j < e; j += 256) atomicAdd(&deg[bin[j] & 127], 1);
    __syncthreads();
    if (tid < TILE) lrow[tid] = deg[tid];
    __syncthreads();
    for (int o = 1; o < TILE; o <<= 1) {
        int v = (tid >= o && tid < TILE) ? lrow[tid - o] : 0;
        __syncthreads();
        if (tid < TILE) lrow[tid] += v;
        __syncthreads();
    }
    if (tid < TILE) {
        const int excl = lrow[tid] - deg[tid];
        rowptr[t * TILE + tid] = b + excl;
        const int node = t * TILE + tid;
        if (node < n) dinv[node] = rsqrtf((float)deg[tid] + 1.0f);
        lrow[tid] = excl;
    }
    if (tid == 0) rowptr[t * TILE + TILE] = e;
    __syncthreads();
    for (int j = b + tid; j < e; j += 256) {
        const unsigned r = bin[j];
        const int dl = r & 127;
        const int p = atomicAdd(&cur[dl], 1);
        csr[b + lrow[dl] + p] = r >> 7;
    }
}

// ---- MFMA bf16 GEMM + dinv-scale epilogue: C = dinv[r]*(A@W), bf16 out -----
// 4 waves/block, 16 rows/wave. 16x16x32 frags; D: col=lane&15, row=(lane>>4)*4+i
template <bool AFP32>
__global__ __launch_bounds__(256) void k_gemm_mfma(
    const void* __restrict__ Ain, const unsigned short* __restrict__ Wf,
    const float* __restrict__ dinv, unsigned short* __restrict__ Cout,
    int nrows) {
    const int tid = threadIdx.x;
    const int wave = tid >> 6, l = tid & 63;
    const int r0w = blockIdx.x * 64 + wave * 16;
    const int mrow = l & 15, koff = (l >> 4) * 8;
    int r = r0w + mrow;
    int rload = (r < nrows) ? r : 0;

    short8 afr[4];
    if (AFP32) {
        const float* A = (const float*)Ain;
#pragma unroll
        for (int ks = 0; ks < 4; ++ks) {
            const float4 lo = *(const float4*)&A[(size_t)rload * 128 + ks * 32 + koff];
            const float4 hi = *(const float4*)&A[(size_t)rload * 128 + ks * 32 + koff + 4];
            short8 t;
            t[0] = (short)f2bf(lo.x); t[1] = (short)f2bf(lo.y);
            t[2] = (short)f2bf(lo.z); t[3] = (short)f2bf(lo.w);
            t[4] = (short)f2bf(hi.x); t[5] = (short)f2bf(hi.y);
            t[6] = (short)f2bf(hi.z); t[7] = (short)f2bf(hi.w);
            afr[ks] = t;
        }
    } else {
        const unsigned short* A = (const unsigned short*)Ain;
#pragma unroll
        for (int ks = 0; ks < 4; ++ks)
            afr[ks] = *(const short8*)&A[(size_t)rload * 128 + ks * 32 + koff];
    }

    f32x4 acc[8];
#pragma unroll
    for (int ct = 0; ct < 8; ++ct) acc[ct] = (f32x4){0.f, 0.f, 0.f, 0.f};

#pragma unroll
    for (int ct = 0; ct < 8; ++ct) {
#pragma unroll
        for (int ks = 0; ks < 4; ++ks) {
            const short8 b = *(const short8*)&Wf[((ct * 4 + ks) * 64 + l) * 8];
            acc[ct] = __builtin_amdgcn_mfma_f32_16x16x32_bf16(afr[ks], b,
                                                              acc[ct], 0, 0, 0);
        }
    }

    const int rs0 = r0w + (l >> 4) * 4;
    const int cc = l & 15;
    float dv[4];
#pragma unroll
    for (int i = 0; i < 4; ++i)
        dv[i] = (rs0 + i < nrows) ? dinv[rs0 + i] : 0.f;
#pragma unroll
    for (int ct = 0; ct < 8; ++ct) {
#pragma unroll
        for (int i = 0; i < 4; ++i) {
            const int rr = rs0 + i;
            if (rr < nrows)
                Cout[(size_t)rr * 128 + ct * 16 + cc] = f2bf(acc[ct][i] * dv[i]);
        }
    }
}

// ---- aggregate: 4 nodes/wave, 16 lanes x uint4/row; pipelined csr prefetch -
// out[d] = relu(dinv[d]*(sum h'[s] + h'[d]) + b); POOL: fused mean-pool,
// no out store (layer-2 output feeds only the pool).
template <bool POOL>
__global__ __launch_bounds__(256) void k_agg(
    const uint4* __restrict__ hp4,  // h' as uint4[n][16]
    const float* __restrict__ dinv, const int* __restrict__ rowptr,
    const unsigned* __restrict__ csr, const float* __restrict__ bias,
    uint4* __restrict__ outp4, float* __restrict__ poolp, int n) {
    __shared__ float psh[4][128];
    const int wave = threadIdx.x >> 6, lane = threadIdx.x & 63;
    const int g = lane >> 4, sl = lane & 15;
    const int node = (blockIdx.x * 4 + wave) * 4 + g;
    const bool valid = node < n;
    const int nd = valid ? node : 0;

    const int rb = rowptr[nd];
    const int deg = valid ? (rowptr[nd + 1] - rb) : 0;
    int maxd = deg;
    maxd = max(maxd, __shfl_xor(maxd, 16));
    maxd = max(maxd, __shfl_xor(maxd, 32));

    const uint4 z = {0u, 0u, 0u, 0u};
    float acc[8];
#pragma unroll
    for (int k = 0; k < 8; ++k) acc[k] = 0.f;
    {
        uint4 self = valid ? hp4[(size_t)nd * 16 + sl] : z;
        acc8(acc, self);
    }

    // software-pipelined: indices for iteration i+1 load while gathers of
    // iteration i are in flight.
    int id[4];
#pragma unroll
    for (int k = 0; k < 4; ++k) id[k] = (k < deg) ? (int)csr[rb + k] : -1;

    for (int j = 0; j < maxd; j += 4) {
        uint4 v[4];
#pragma unroll
        for (int k = 0; k < 4; ++k)
            v[k] = (id[k] >= 0) ? hp4[(size_t)id[k] * 16 + sl] : z;
        int nid[4];
#pragma unroll
        for (int k = 0; k < 4; ++k) {
            const int jj = j + 4 + k;
            nid[k] = (jj < deg) ? (int)csr[rb + jj] : -1;
        }
#pragma unroll
        for (int k = 0; k < 4; ++k) acc8(acc, v[k]);
#pragma unroll
        for (int k = 0; k < 4; ++k) id[k] = nid[k];
    }

    const float dv = valid ? dinv[nd] : 0.f;
    const float4 b0 = ((const float4*)bias)[sl * 2];
    const float4 b1 = ((const float4*)bias)[sl * 2 + 1];
    float o[8];
    o[0] = fmaxf(acc[0] * dv + b0.x, 0.f);
    o[1] = fmaxf(acc[1] * dv + b0.y, 0.f);
    o[2] = fmaxf(acc[2] * dv + b0.z, 0.f);
    o[3] = fmaxf(acc[3] * dv + b0.w, 0.f);
    o[4] = fmaxf(acc[4] * dv + b1.x, 0.f);
    o[5] = fmaxf(acc[5] * dv + b1.y, 0.f);
    o[6] = fmaxf(acc[6] * dv + b1.z, 0.f);
    o[7] = fmaxf(acc[7] * dv + b1.w, 0.f);
    if (!valid) {
#pragma unroll
        for (int k = 0; k < 8; ++k) o[k] = 0.f;
    }

    if (!POOL) {
        if (valid) {
            uint4 ov;
            ov.x = ((unsigned)f2bf(o[1]) << 16) | f2bf(o[0]);
            ov.y = ((unsigned)f2bf(o[3]) << 16) | f2bf(o[2]);
            ov.z = ((unsigned)f2bf(o[5]) << 16) | f2bf(o[4]);
            ov.w = ((unsigned)f2bf(o[7]) << 16) | f2bf(o[6]);
            outp4[(size_t)nd * 16 + sl] = ov;
        }
    } else {
        // column sums: reduce over 4 groups in-wave, 4 waves via LDS,
        // then one padded atomicAdd per column into the XCD-split slot.
        float s[8];
#pragma unroll
        for (int k = 0; k < 8; ++k) {
            float t = o[k];
            t += __shfl_xor(t, 16);
            t += __shfl_xor(t, 32);
            s[k] = t;
        }
        if (lane < 16) {
#pragma unroll
            for (int k = 0; k < 8; ++k) psh[wave][sl * 8 + k] = s[k];
        }
        __syncthreads();
        const int tid = threadIdx.x;
        if (tid < 128) {
            const float t =
                psh[0][tid] + psh[1][tid] + psh[2][tid] + psh[3][tid];
            atomicAdd(&poolp[((blockIdx.x & 7) << 11) + tid * 16], t);
        }
    }
}

// ---- MLP head: single block, 128 threads -----------------------------------
__global__ __launch_bounds__(128) void k_mlp(
    const float* __restrict__ poolp, const float* __restrict__ w11,
    const float* __restrict__ b11, const float* __restrict__ w12,
    const float* __restrict__ b12, const float* __restrict__ w21,
    const float* __restrict__ b21, const float* __restrict__ w22,
    const float* __restrict__ b22, float* __restrict__ out, int n) {
    __shared__ float g[128], t1[128], t2[128], t3[128], red[128];
    const int tid = threadIdx.x;
    float gs = 0.f;
#pragma unroll
    for (int x = 0; x < 8; ++x) gs += poolp[x * 2048 + tid * 16];
    g[tid] = gs * (1.0f / (float)n);
    __syncthreads();

    float s = b11[tid];
    for (int k = 0; k < 128; ++k) s += g[k] * w11[k * 128 + tid];
    t1[tid] = fmaxf(s, 0.f);
    __syncthreads();

    s = b12[tid];
    for (int k = 0; k < 128; ++k) s += t1[k] * w12[k * 128 + tid];
    t2[tid] = s;
    __syncthreads();

    s = b21[tid];
    for (int k = 0; k < 128; ++k) s += t2[k] * w21[k * 128 + tid];
    t3[tid] = fmaxf(s, 0.f);
    __syncthreads();

    red[tid] = t3[tid] * w22[tid];
    __syncthreads();
    if (tid == 0) {
        float z = b22[0];
        for (int k = 0; k < 128; ++k) z += red[k];
        out[0] = 1.0f / (1.0f + expf(-z));
    }
}

extern "C" void kernel_launch(void* const* d_in, const int* in_sizes, int n_in,
                              void* d_out, int out_size, void* d_ws,
                              size_t ws_size, hipStream_t stream) {
    const float* x = (const float*)d_in[0];
    const int* ei = (const int*)d_in[1];
    const float* c1w = (const float*)d_in[2];
    const float* c1b = (const float*)d_in[3];
    const float* c2w = (const float*)d_in[4];
    const float* c2b = (const float*)d_in[5];
    const float* f1w1 = (const float*)d_in[6];
    const float* f1b1 = (const float*)d_in[7];
    const float* f1w2 = (const float*)d_in[8];
    const float* f1b2 = (const float*)d_in[9];
    const float* f2w1 = (const float*)d_in[10];
    const float* f2b1 = (const float*)d_in[11];
    const float* f2w2 = (const float*)d_in[12];
    const float* f2b2 = (const float*)d_in[13];
    float* out = (float*)d_out;

    const int N = in_sizes[0] / 128;
    const int E = in_sizes[1] / 2;
    const int NT = (N + TILE - 1) / TILE;    // 391
    const int NB = (E + EPB - 1) / EPB;      // 196
    const int NTB = NT * NB;                 // 76,636
    const int nbScan = (NTB + 255) / 256;    // 300 (<=512: state fits)

    char* ws = (char*)d_ws;
    size_t off = 0;
    auto alloc = [&](size_t b) {
        size_t o = off;
        off += (b + 255) & ~(size_t)255;
        return o;
    };
    int* hist = (int*)(ws + alloc((size_t)NTB * 4));
    int* histS = (int*)(ws + alloc((size_t)NTB * 4));
    int* state = (int*)(ws + alloc(2048));
    unsigned* bin = (unsigned*)(ws + alloc((size_t)E * 4));
    unsigned* csr = (unsigned*)(ws + alloc((size_t)E * 4));
    int* rowptr = (int*)(ws + alloc((size_t)(NT * TILE + 1) * 4));
    float* dinv = (float*)(ws + alloc((size_t)N * 4));
    float* poolp = (float*)(ws + alloc(8 * 2048 * 4));  // 8 XCD slots, 64B-padded
    unsigned short* wf1 = (unsigned short*)(ws + alloc(16384 * 2));
    unsigned short* wf2 = (unsigned short*)(ws + alloc(16384 * 2));
    unsigned short* hbuf = (unsigned short*)(ws + alloc((size_t)N * 128 * 2));
    unsigned short* abuf = (unsigned short*)(ws + alloc((size_t)N * 128 * 2));

    const int nbG = (N + 63) / 64;  // 782

    k_histA<<<NB, 256, 0, stream>>>(ei + E, hist, poolp, state, c1w, c2w, wf1,
                                    wf2, E, NT, NB);
    k_scanLB<<<nbScan, 256, 0, stream>>>(hist, histS, state, NTB);
    k_passB<<<NB, 256, 0, stream>>>(ei, histS, bin, E, NT, NB);
    k_sortT<<<NT, 256, 0, stream>>>(bin, histS, csr, rowptr, dinv, N, NT, NB, E);

    k_gemm_mfma<true><<<nbG, 256, 0, stream>>>(x, wf1, dinv, hbuf, N);
    k_agg<false><<<(N + 15) / 16, 256, 0, stream>>>(
        (const uint4*)hbuf, dinv, rowptr, csr, c1b, (uint4*)abuf, poolp, N);
    k_gemm_mfma<false><<<nbG, 256, 0, stream>>>(abuf, wf2, dinv, hbuf, N);
    k_agg<true><<<(N + 15) / 16, 256, 0, stream>>>(
        (const uint4*)hbuf, dinv, rowptr, csr, c2b, (uint4*)abuf, poolp, N);

    k_mlp<<<1, 128, 0, stream>>>(poolp, f1w1, f1b1, f1w2, f1b2, f2w1, f2b1,
                                 f2w2, f2b2, out, N);
}

// Round 13
// 289.589 us; speedup vs baseline: 1.0057x; 1.0006x over previous
//
#include <hip/hip_runtime.h>
#include <hip/hip_bf16.h>

// ---------------------------------------------------------------------------
// GCN graph classifier: 2x GCNConv(relu) -> mean pool -> MLP -> sigmoid
// Round 13: agg = 8-deep gathers WITH __launch_bounds__(256,4) so the
// register allocator can actually keep 8 uint4 loads in flight (rounds
// 10/12 failed at VGPR=40/32); psh LDS only in POOL instantiation.
// Keep: decoupled-lookback scan, mean-pool fused into layer-2 agg,
// stable-multisplit build -> sorted CSR, MFMA GEMMs with dinv epilogue.
// ---------------------------------------------------------------------------

#define TILE 128
#define EPB 4096  // edges per multisplit block

using short8 = __attribute__((ext_vector_type(8))) short;   // 8 bf16 (4 VGPR)
using f32x4  = __attribute__((ext_vector_type(4))) float;   // MFMA accum

__device__ inline unsigned short f2bf(float f) {  // RNE fp32 -> bf16
    unsigned u = __float_as_uint(f);
    u = (u + 0x7fff + ((u >> 16) & 1)) >> 16;
    return (unsigned short)u;
}
__device__ inline float bf2f(unsigned short b) {
    return __uint_as_float((unsigned)b << 16);
}
__device__ inline void acc8(float* a, const uint4 v) {
    a[0] += bf2f((unsigned short)(v.x & 0xffff));
    a[1] += bf2f((unsigned short)(v.x >> 16));
    a[2] += bf2f((unsigned short)(v.y & 0xffff));
    a[3] += bf2f((unsigned short)(v.y >> 16));
    a[4] += bf2f((unsigned short)(v.z & 0xffff));
    a[5] += bf2f((unsigned short)(v.z >> 16));
    a[6] += bf2f((unsigned short)(v.w & 0xffff));
    a[7] += bf2f((unsigned short)(v.w >> 16));
}

// ---- histA: per-block LDS histogram of dst tiles; + prepw + zero pool/state
// wf[((ct*4+ks)*64+l)*8+j] = W[ks*32 + (l>>4)*8 + j][ct*16 + (l&15)]
__global__ __launch_bounds__(256) void k_histA(
    const int* __restrict__ dst, int* __restrict__ hist,
    float* __restrict__ poolp, int* __restrict__ state,
    const float* __restrict__ w1, const float* __restrict__ w2,
    unsigned short* __restrict__ wf1, unsigned short* __restrict__ wf2,
    int e, int nt, int nb) {
    __shared__ int h[512];
    const int tid = threadIdx.x, b = blockIdx.x;
    for (int i = tid; i < 512; i += 256) h[i] = 0;
    if (b < 8)  // zero the 8 XCD-split padded pool accumulators (2048 each)
        for (int i = tid; i < 2048; i += 256) poolp[b * 2048 + i] = 0.0f;
    if (b == 8)  // zero scan lookback state
        for (int i = tid; i < 512; i += 256) state[i] = 0;
    // fused weight prep: blocks 0..127 each convert 256 elements
    if (b < 128) {
        const int t = b * 256 + tid;  // 0..32767
        const int i = t & 16383;
        const int j = i & 7;
        const int l = (i >> 3) & 63;
        const int ks = (i >> 9) & 3;
        const int ct = (i >> 11) & 7;
        const int k = ks * 32 + (l >> 4) * 8 + j;
        const int c = ct * 16 + (l & 15);
        if (t < 16384)
            wf1[i] = f2bf(w1[k * 128 + c]);
        else
            wf2[i] = f2bf(w2[k * 128 + c]);
    }
    __syncthreads();
    const int base = b * EPB;
#pragma unroll
    for (int k = 0; k < EPB / 256; ++k) {
        const int i = base + k * 256 + tid;
        if (i < e) atomicAdd(&h[dst[i] >> 7], 1);
    }
    __syncthreads();
    for (int t = tid; t < nt; t += 256) hist[t * nb + b] = h[t];
}

// ---- single-kernel exclusive scan: decoupled lookback (wave-parallel) ------
// state[b]: bit31 = inclusive-prefix known, bit30 = aggregate known, low 30 = value
__global__ __launch_bounds__(256) void k_scanLB(const int* __restrict__ in,
                                                int* __restrict__ outp,
                                                int* __restrict__ state,
                                                int n) {
    __shared__ int sh[256];
    __shared__ int sprefix;
    const int b = blockIdx.x, tid = threadIdx.x;
    const int i = b * 256 + tid;
    int v = (i < n) ? in[i] : 0;
    sh[tid] = v;
    __syncthreads();
    for (int o = 1; o < 256; o <<= 1) {
        int t = (tid >= o) ? sh[tid - o] : 0;
        __syncthreads();
        sh[tid] += t;
        __syncthreads();
    }
    const int total = sh[255];
    if (tid == 0) {
        const int val =
            (b == 0) ? (total | (int)0x80000000) : (total | 0x40000000);
        __hip_atomic_store(&state[b], val, __ATOMIC_RELEASE,
                           __HIP_MEMORY_SCOPE_AGENT);
        if (b == 0) sprefix = 0;
    }
    if (b > 0 && tid < 64) {
        int pre = 0;
        int j = b - 1;
        while (true) {
            const int jj = j - tid;
            int s = (jj >= 0)
                        ? __hip_atomic_load(&state[jj], __ATOMIC_ACQUIRE,
                                            __HIP_MEMORY_SCOPE_AGENT)
                        : (int)0x80000000;  // virtual inclusive 0 before block 0
            const unsigned long long incl =
                __ballot(((unsigned)s & 0x80000000u) != 0);
            const unsigned long long inval = __ballot((s & 0xC0000000) == 0);
            if (incl != 0) {
                const int li = (int)(__ffsll((unsigned long long)incl) - 1);
                const unsigned long long below =
                    (li == 0) ? 0ULL : ((1ULL << li) - 1ULL);
                if (inval & below) continue;  // unknown entry nearer than inclusive
                int c = (tid <= li) ? (s & 0x3fffffff) : 0;
#pragma unroll
                for (int o2 = 1; o2 < 64; o2 <<= 1) c += __shfl_xor(c, o2);
                pre += c;
                break;
            } else {
                if (inval != 0) continue;  // some aggregates not yet published
                int c = s & 0x3fffffff;    // all 64 are valid aggregates
#pragma unroll
                for (int o2 = 1; o2 < 64; o2 <<= 1) c += __shfl_xor(c, o2);
                pre += c;
                j -= 64;
            }
        }
        if (tid == 0) {
            __hip_atomic_store(&state[b],
                               ((total + pre) & 0x3fffffff) | (int)0x80000000,
                               __ATOMIC_RELEASE, __HIP_MEMORY_SCOPE_AGENT);
            sprefix = pre;
        }
    }
    __syncthreads();
    if (i < n) outp[i] = sh[tid] - v + sprefix;
}

// ---- passB: stable multisplit scatter into exact (tile,block) chunks -------
__global__ __launch_bounds__(256) void k_passB(const int* __restrict__ ei,
                                               const int* __restrict__ histS,
                                               unsigned* __restrict__ bin,
                                               int e, int nt, int nb) {
    __shared__ int cnt[512], basei[512];
    const int tid = threadIdx.x, b = blockIdx.x;
    for (int i = tid; i < 512; i += 256) cnt[i] = 0;
    for (int t = tid; t < nt; t += 256) basei[t] = histS[t * nb + b];
    __syncthreads();
    const int base = b * EPB;
#pragma unroll
    for (int k = 0; k < EPB / 256; ++k) {
        const int i = base + k * 256 + tid;
        if (i < e) {
            const int s = ei[i];
            const int d = ei[e + i];
            const int t = d >> 7;
            const int r = atomicAdd(&cnt[t], 1);
            bin[basei[t] + r] = ((unsigned)s << 7) | (unsigned)(d & 127);
        }
    }
}

// ---- per-tile LDS counting sort: bin segment -> sorted csr + rowptr + dinv -
__global__ __launch_bounds__(256) void k_sortT(const unsigned* __restrict__ bin,
                                               const int* __restrict__ histS,
                                               unsigned* __restrict__ csr,
                                               int* __restrict__ rowptr,
                                               float* __restrict__ dinv,
                                               int n, int nt, int nb, int etot) {
    __shared__ int deg[TILE], lrow[TILE], cur[TILE];
    const int t = blockIdx.x, tid = threadIdx.x;
    if (tid < TILE) {
        deg[tid] = 0;
        cur[tid] = 0;
    }
    __syncthreads();
    const int b = histS[t * nb];
    const int e = (t + 1 < nt) ? histS[(t + 1) * nb] : etot;
    for (int j = b + tid; j < e; j += 256) atomicAdd(&deg[bin[j] & 127], 1);
    __syncthreads();
    if (tid < TILE) lrow[tid] = deg[tid];
    __syncthreads();
    for (int o = 1; o < TILE; o <<= 1) {
        int v = (tid >= o && tid < TILE) ? lrow[tid - o] : 0;
        __syncthreads();
        if (tid < TILE) lrow[tid] += v;
        __syncthreads();
    }
    if (tid < TILE) {
        const int excl = lrow[tid] - deg[tid];
        rowptr[t * TILE + tid] = b + excl;
        const int node = t * TILE + tid;
        if (node < n) dinv[node] = rsqrtf((float)deg[tid] + 1.0f);
        lrow[tid] = excl;
    }
    if (tid == 0) rowptr[t * TILE + TILE] = e;
    __syncthreads();
    for (int j = b + tid; j < e; j += 256) {
        const unsigned r = bin[j];
        const int dl = r & 127;
        const int p = atomicAdd(&cur[dl], 1);
        csr[b + lrow[dl] + p] = r >> 7;
    }
}

// ---- MFMA bf16 GEMM + dinv-scale epilogue: C = dinv[r]*(A@W), bf16 out -----
// 4 waves/block, 16 rows/wave. 16x16x32 frags; D: col=lane&15, row=(lane>>4)*4+i
template <bool AFP32>
__global__ __launch_bounds__(256) void k_gemm_mfma(
    const void* __restrict__ Ain, const unsigned short* __restrict__ Wf,
    const float* __restrict__ dinv, unsigned short* __restrict__ Cout,
    int nrows) {
    const int tid = threadIdx.x;
    const int wave = tid >> 6, l = tid & 63;
    const int r0w = blockIdx.x * 64 + wave * 16;
    const int mrow = l & 15, koff = (l >> 4) * 8;
    int r = r0w + mrow;
    int rload = (r < nrows) ? r : 0;

    short8 afr[4];
    if (AFP32) {
        const float* A = (const float*)Ain;
#pragma unroll
        for (int ks = 0; ks < 4; ++ks) {
            const float4 lo = *(const float4*)&A[(size_t)rload * 128 + ks * 32 + koff];
            const float4 hi = *(const float4*)&A[(size_t)rload * 128 + ks * 32 + koff + 4];
            short8 t;
            t[0] = (short)f2bf(lo.x); t[1] = (short)f2bf(lo.y);
            t[2] = (short)f2bf(lo.z); t[3] = (short)f2bf(lo.w);
            t[4] = (short)f2bf(hi.x); t[5] = (short)f2bf(hi.y);
            t[6] = (short)f2bf(hi.z); t[7] = (short)f2bf(hi.w);
            afr[ks] = t;
        }
    } else {
        const unsigned short* A = (const unsigned short*)Ain;
#pragma unroll
        for (int ks = 0; ks < 4; ++ks)
            afr[ks] = *(const short8*)&A[(size_t)rload * 128 + ks * 32 + koff];
    }

    f32x4 acc[8];
#pragma unroll
    for (int ct = 0; ct < 8; ++ct) acc[ct] = (f32x4){0.f, 0.f, 0.f, 0.f};

#pragma unroll
    for (int ct = 0; ct < 8; ++ct) {
#pragma unroll
        for (int ks = 0; ks < 4; ++ks) {
            const short8 b = *(const short8*)&Wf[((ct * 4 + ks) * 64 + l) * 8];
            acc[ct] = __builtin_amdgcn_mfma_f32_16x16x32_bf16(afr[ks], b,
                                                              acc[ct], 0, 0, 0);
        }
    }

    const int rs0 = r0w + (l >> 4) * 4;
    const int cc = l & 15;
    float dv[4];
#pragma unroll
    for (int i = 0; i < 4; ++i)
        dv[i] = (rs0 + i < nrows) ? dinv[rs0 + i] : 0.f;
#pragma unroll
    for (int ct = 0; ct < 8; ++ct) {
#pragma unroll
        for (int i = 0; i < 4; ++i) {
            const int rr = rs0 + i;
            if (rr < nrows)
                Cout[(size_t)rr * 128 + ct * 16 + cc] = f2bf(acc[ct][i] * dv[i]);
        }
    }
}

// ---- aggregate: 4 nodes/wave, 16 lanes x uint4/row, 8 gathers in flight ----
// __launch_bounds__(256,4): min 4 waves/EU -> VGPR cap 128, so the allocator
// can hold 8 uint4 loads live (rounds 10/12 got rationed to 40/32 VGPR).
// out[d] = relu(dinv[d]*(sum h'[s] + h'[d]) + b); POOL: fused mean-pool.
template <bool POOL>
__global__ __launch_bounds__(256, 4) void k_agg(
    const uint4* __restrict__ hp4,  // h' as uint4[n][16]
    const float* __restrict__ dinv, const int* __restrict__ rowptr,
    const unsigned* __restrict__ csr, const float* __restrict__ bias,
    uint4* __restrict__ outp4, float* __restrict__ poolp, int n) {
    const int wave = threadIdx.x >> 6, lane = threadIdx.x & 63;
    const int g = lane >> 4, sl = lane & 15;
    const int node = (blockIdx.x * 4 + wave) * 4 + g;
    const bool valid = node < n;
    const int nd = valid ? node : 0;

    const int rb = rowptr[nd];
    const int deg = valid ? (rowptr[nd + 1] - rb) : 0;
    int maxd = deg;
    maxd = max(maxd, __shfl_xor(maxd, 16));
    maxd = max(maxd, __shfl_xor(maxd, 32));

    const uint4 z = {0u, 0u, 0u, 0u};
    float acc[8];
#pragma unroll
    for (int k = 0; k < 8; ++k) acc[k] = 0.f;
    {
        uint4 self = valid ? hp4[(size_t)nd * 16 + sl] : z;
        acc8(acc, self);
    }

    int j = 0;
    for (; j + 7 < maxd; j += 8) {  // 8 gathers in flight
        int id[8];
#pragma unroll
        for (int k = 0; k < 8; ++k)
            id[k] = (j + k < deg) ? (int)csr[rb + j + k] : -1;
        uint4 v[8];
#pragma unroll
        for (int k = 0; k < 8; ++k)
            v[k] = (id[k] >= 0) ? hp4[(size_t)id[k] * 16 + sl] : z;
#pragma unroll
        for (int k = 0; k < 8; ++k) acc8(acc, v[k]);
    }
    for (; j < maxd; j += 4) {
        int id[4];
#pragma unroll
        for (int k = 0; k < 4; ++k)
            id[k] = (j + k < deg) ? (int)csr[rb + j + k] : -1;
        uint4 v[4];
#pragma unroll
        for (int k = 0; k < 4; ++k)
            v[k] = (id[k] >= 0) ? hp4[(size_t)id[k] * 16 + sl] : z;
#pragma unroll
        for (int k = 0; k < 4; ++k) acc8(acc, v[k]);
    }

    const float dv = valid ? dinv[nd] : 0.f;
    const float4 b0 = ((const float4*)bias)[sl * 2];
    const float4 b1 = ((const float4*)bias)[sl * 2 + 1];
    float o[8];
    o[0] = fmaxf(acc[0] * dv + b0.x, 0.f);
    o[1] = fmaxf(acc[1] * dv + b0.y, 0.f);
    o[2] = fmaxf(acc[2] * dv + b0.z, 0.f);
    o[3] = fmaxf(acc[3] * dv + b0.w, 0.f);
    o[4] = fmaxf(acc[4] * dv + b1.x, 0.f);
    o[5] = fmaxf(acc[5] * dv + b1.y, 0.f);
    o[6] = fmaxf(acc[6] * dv + b1.z, 0.f);
    o[7] = fmaxf(acc[7] * dv + b1.w, 0.f);
    if (!valid) {
#pragma unroll
        for (int k = 0; k < 8; ++k) o[k] = 0.f;
    }

    if constexpr (!POOL) {
        if (valid) {
            uint4 ov;
            ov.x = ((unsigned)f2bf(o[1]) << 16) | f2bf(o[0]);
            ov.y = ((unsigned)f2bf(o[3]) << 16) | f2bf(o[2]);
            ov.z = ((unsigned)f2bf(o[5]) << 16) | f2bf(o[4]);
            ov.w = ((unsigned)f2bf(o[7]) << 16) | f2bf(o[6]);
            outp4[(size_t)nd * 16 + sl] = ov;
        }
    } else {
        __shared__ float psh[4][128];
        // column sums: reduce over 4 groups in-wave, 4 waves via LDS,
        // then one padded atomicAdd per column into the XCD-split slot.
        float s[8];
#pragma unroll
        for (int k = 0; k < 8; ++k) {
            float t = o[k];
            t += __shfl_xor(t, 16);
            t += __shfl_xor(t, 32);
            s[k] = t;
        }
        if (lane < 16) {
#pragma unroll
            for (int k = 0; k < 8; ++k) psh[wave][sl * 8 + k] = s[k];
        }
        __syncthreads();
        const int tid = threadIdx.x;
        if (tid < 128) {
            const float t =
                psh[0][tid] + psh[1][tid] + psh[2][tid] + psh[3][tid];
            atomicAdd(&poolp[((blockIdx.x & 7) << 11) + tid * 16], t);
        }
    }
}

// ---- MLP head: single block, 128 threads -----------------------------------
__global__ __launch_bounds__(128) void k_mlp(
    const float* __restrict__ poolp, const float* __restrict__ w11,
    const float* __restrict__ b11, const float* __restrict__ w12,
    const float* __restrict__ b12, const float* __restrict__ w21,
    const float* __restrict__ b21, const float* __restrict__ w22,
    const float* __restrict__ b22, float* __restrict__ out, int n) {
    __shared__ float g[128], t1[128], t2[128], t3[128], red[128];
    const int tid = threadIdx.x;
    float gs = 0.f;
#pragma unroll
    for (int x = 0; x < 8; ++x) gs += poolp[x * 2048 + tid * 16];
    g[tid] = gs * (1.0f / (float)n);
    __syncthreads();

    float s = b11[tid];
    for (int k = 0; k < 128; ++k) s += g[k] * w11[k * 128 + tid];
    t1[tid] = fmaxf(s, 0.f);
    __syncthreads();

    s = b12[tid];
    for (int k = 0; k < 128; ++k) s += t1[k] * w12[k * 128 + tid];
    t2[tid] = s;
    __syncthreads();

    s = b21[tid];
    for (int k = 0; k < 128; ++k) s += t2[k] * w21[k * 128 + tid];
    t3[tid] = fmaxf(s, 0.f);
    __syncthreads();

    red[tid] = t3[tid] * w22[tid];
    __syncthreads();
    if (tid == 0) {
        float z = b22[0];
        for (int k = 0; k < 128; ++k) z += red[k];
        out[0] = 1.0f / (1.0f + expf(-z));
    }
}

extern "C" void kernel_launch(void* const* d_in, const int* in_sizes, int n_in,
                              void* d_out, int out_size, void* d_ws,
                              size_t ws_size, hipStream_t stream) {
    const float* x = (const float*)d_in[0];
    const int* ei = (const int*)d_in[1];
    const float* c1w = (const float*)d_in[2];
    const float* c1b = (const float*)d_in[3];
    const float* c2w = (const float*)d_in[4];
    const float* c2b = (const float*)d_in[5];
    const float* f1w1 = (const float*)d_in[6];
    const float* f1b1 = (const float*)d_in[7];
    const float* f1w2 = (const float*)d_in[8];
    const float* f1b2 = (const float*)d_in[9];
    const float* f2w1 = (const float*)d_in[10];
    const float* f2b1 = (const float*)d_in[11];
    const float* f2w2 = (const float*)d_in[12];
    const float* f2b2 = (const float*)d_in[13];
    float* out = (float*)d_out;

    const int N = in_sizes[0] / 128;
    const int E = in_sizes[1] / 2;
    const int NT = (N + TILE - 1) / TILE;    // 391
    const int NB = (E + EPB - 1) / EPB;      // 196
    const int NTB = NT * NB;                 // 76,636
    const int nbScan = (NTB + 255) / 256;    // 300 (<=512: state fits)

    char* ws = (char*)d_ws;
    size_t off = 0;
    auto alloc = [&](size_t b) {
        size_t o = off;
        off += (b + 255) & ~(size_t)255;
        return o;
    };
    int* hist = (int*)(ws + alloc((size_t)NTB * 4));
    int* histS = (int*)(ws + alloc((size_t)NTB * 4));
    int* state = (int*)(ws + alloc(2048));
    unsigned* bin = (unsigned*)(ws + alloc((size_t)E * 4));
    unsigned* csr = (unsigned*)(ws + alloc((size_t)E * 4));
    int* rowptr = (int*)(ws + alloc((size_t)(NT * TILE + 1) * 4));
    float* dinv = (float*)(ws + alloc((size_t)N * 4));
    float* poolp = (float*)(ws + alloc(8 * 2048 * 4));  // 8 XCD slots, 64B-padded
    unsigned short* wf1 = (unsigned short*)(ws + alloc(16384 * 2));
    unsigned short* wf2 = (unsigned short*)(ws + alloc(16384 * 2));
    unsigned short* hbuf = (unsigned short*)(ws + alloc((size_t)N * 128 * 2));
    unsigned short* abuf = (unsigned short*)(ws + alloc((size_t)N * 128 * 2));

    const int nbG = (N + 63) / 64;  // 782

    k_histA<<<NB, 256, 0, stream>>>(ei + E, hist, poolp, state, c1w, c2w, wf1,
                                    wf2, E, NT, NB);
    k_scanLB<<<nbScan, 256, 0, stream>>>(hist, histS, state, NTB);
    k_passB<<<NB, 256, 0, stream>>>(ei, histS, bin, E, NT, NB);
    k_sortT<<<NT, 256, 0, stream>>>(bin, histS, csr, rowptr, dinv, N, NT, NB, E);

    k_gemm_mfma<true><<<nbG, 256, 0, stream>>>(x, wf1, dinv, hbuf, N);
    k_agg<false><<<(N + 15) / 16, 256, 0, stream>>>(
        (const uint4*)hbuf, dinv, rowptr, csr, c1b, (uint4*)abuf, poolp, N);
    k_gemm_mfma<false><<<nbG, 256, 0, stream>>>(abuf, wf2, dinv, hbuf, N);
    k_agg<true><<<(N + 15) / 16, 256, 0, stream>>>(
        (const uint4*)hbuf, dinv, rowptr, csr, c2b, (uint4*)abuf, poolp, N);

    k_mlp<<<1, 128, 0, stream>>>(poolp, f1w1, f1b1, f1w2, f1b2, f2w1, f2b1,
                                 f2w2, f2b2, out, N);
}